// Round 1
// baseline (109.638 us; speedup 1.0000x reference)
//
#include <hip/hip_runtime.h>

#define B_   4
#define Q_   256
#define C_   1024
#define H_   128
#define NEG  0.01f

// ---------------------------------------------------------------------------
// Kernel 1: hq[b,q,k] = sum_h query[b,q,h]*Ww[k,h]
//           hc[b,c,k] = sum_h context[b,c,h]*Ww[k,H+h] + bw[k]
// 8 rows per block, 128 threads (thread = output k). Input rows are read as
// wave-uniform float4 loads (scalar-cache friendly); Ww row k is per-thread
// contiguous (L1/L2 resident, 128 KB total).
// ---------------------------------------------------------------------------
__global__ __launch_bounds__(128) void proj_kernel(
    const float* __restrict__ query, const float* __restrict__ context,
    const float* __restrict__ Ww, const float* __restrict__ bw,
    float* __restrict__ hq, float* __restrict__ hc)
{
    const int blk = blockIdx.x;
    const int k = threadIdx.x;
    const bool is_q = (blk < (B_ * Q_ / 8));              // 128 blocks for hq
    const int row0 = is_q ? (blk * 8) : ((blk - B_ * Q_ / 8) * 8);
    const float* __restrict__ in = is_q ? query : context;
    float* __restrict__ out = is_q ? hq : hc;

    const float4* __restrict__ Wrow =
        reinterpret_cast<const float4*>(Ww + k * (2 * H_) + (is_q ? 0 : H_));
    const float4* __restrict__ in4 =
        reinterpret_cast<const float4*>(in + row0 * H_);

    float acc[8] = {0.f, 0.f, 0.f, 0.f, 0.f, 0.f, 0.f, 0.f};
    #pragma unroll 8
    for (int h4 = 0; h4 < H_ / 4; ++h4) {
        const float4 wvv = Wrow[h4];
        #pragma unroll
        for (int r = 0; r < 8; ++r) {
            const float4 iv = in4[r * (H_ / 4) + h4];     // wave-uniform
            acc[r] += iv.x * wvv.x + iv.y * wvv.y + iv.z * wvv.z + iv.w * wvv.w;
        }
    }
    const float bias = is_q ? 0.f : bw[k];
    #pragma unroll
    for (int r = 0; r < 8; ++r)
        out[(row0 + r) * H_ + k] = acc[r] + bias;
}

// ---------------------------------------------------------------------------
// Kernel 2: per block = (b, 4 consecutive q). 512 threads (8 waves).
// Phase 1: thread owns c in {t, t+512}, accumulates scores for all 4 q
//          (hc row read once per block; hq/Ws are wave-uniform loads).
// Phase 2: softmax over c per q (wave shuffle butterflies + LDS combine).
// Phase 3: attn_output via 16-way c-split partial sums + LDS reduction;
//          context element read exactly once per block.
// bs is omitted: softmax is shift-invariant, both outputs are post-softmax.
// ---------------------------------------------------------------------------
__global__ __launch_bounds__(512) void attn_kernel(
    const float* __restrict__ hq, const float* __restrict__ hc,
    const float* __restrict__ Ws, const float* __restrict__ context,
    float* __restrict__ outA, float* __restrict__ outP)
{
    const int b  = blockIdx.x >> 6;          // 4 b
    const int q0 = (blockIdx.x & 63) * 4;    // 64 q-groups per b
    const int t  = threadIdx.x;
    const int wv = t >> 6;                   // wave id 0..7

    __shared__ float4 attn4_s[C_];           // 16 KiB: attn packed {q0..q3} per c
    __shared__ float  red[16 * 4 * H_];      // 32 KiB: phase-3 partials
    __shared__ float  wred[8][4];
    __shared__ float  wsum[8][4];

    const float4* __restrict__ hq4  = reinterpret_cast<const float4*>(hq);
    const float4* __restrict__ hc4  = reinterpret_cast<const float4*>(hc);
    const float4* __restrict__ ws4  = reinterpret_cast<const float4*>(Ws);
    const float4* __restrict__ ctx4 = reinterpret_cast<const float4*>(context);

    // ---- phase 1: scores
    float s[4][2] = {{0.f,0.f},{0.f,0.f},{0.f,0.f},{0.f,0.f}};
    const int c0 = t, c1 = t + 512;
    #pragma unroll 4
    for (int k0 = 0; k0 < H_ / 4; ++k0) {
        const float4 wsv = ws4[k0];
        float4 hqv[4];
        #pragma unroll
        for (int q = 0; q < 4; ++q)
            hqv[q] = hq4[(b * Q_ + q0 + q) * (H_ / 4) + k0];  // wave-uniform
        #pragma unroll
        for (int ci = 0; ci < 2; ++ci) {
            const int c = ci ? c1 : c0;
            const float4 hcv = hc4[(b * C_ + c) * (H_ / 4) + k0];
            #pragma unroll
            for (int q = 0; q < 4; ++q) {
                float x0 = hqv[q].x + hcv.x;
                float x1 = hqv[q].y + hcv.y;
                float x2 = hqv[q].z + hcv.z;
                float x3 = hqv[q].w + hcv.w;
                x0 = fmaxf(x0, NEG * x0);   // leaky_relu, 2 VALU ops
                x1 = fmaxf(x1, NEG * x1);
                x2 = fmaxf(x2, NEG * x2);
                x3 = fmaxf(x3, NEG * x3);
                s[q][ci] += wsv.x * x0 + wsv.y * x1 + wsv.z * x2 + wsv.w * x3;
            }
        }
    }

    // ---- phase 2: softmax over the 1024 c per q row
    float m[4];
    #pragma unroll
    for (int q = 0; q < 4; ++q) {
        float v = fmaxf(s[q][0], s[q][1]);
        #pragma unroll
        for (int off = 32; off >= 1; off >>= 1)
            v = fmaxf(v, __shfl_xor(v, off, 64));
        m[q] = v;
    }
    if ((t & 63) == 0) {
        #pragma unroll
        for (int q = 0; q < 4; ++q) wred[wv][q] = m[q];
    }
    __syncthreads();
    #pragma unroll
    for (int q = 0; q < 4; ++q) {
        float v = wred[0][q];
        #pragma unroll
        for (int i = 1; i < 8; ++i) v = fmaxf(v, wred[i][q]);
        m[q] = v;
    }
    float e[4][2], p[4];
    #pragma unroll
    for (int q = 0; q < 4; ++q) {
        e[q][0] = __expf(s[q][0] - m[q]);
        e[q][1] = __expf(s[q][1] - m[q]);
        float v = e[q][0] + e[q][1];
        #pragma unroll
        for (int off = 32; off >= 1; off >>= 1)
            v += __shfl_xor(v, off, 64);
        p[q] = v;
    }
    if ((t & 63) == 0) {
        #pragma unroll
        for (int q = 0; q < 4; ++q) wsum[wv][q] = p[q];
    }
    __syncthreads();
    float rS[4];
    #pragma unroll
    for (int q = 0; q < 4; ++q) {
        float S = wsum[0][q];
        #pragma unroll
        for (int i = 1; i < 8; ++i) S += wsum[i][q];
        rS[q] = 1.0f / S;
    }
    float a0[4], a1[4];
    #pragma unroll
    for (int q = 0; q < 4; ++q) {
        a0[q] = e[q][0] * rS[q];
        a1[q] = e[q][1] * rS[q];
    }
    attn4_s[c0] = make_float4(a0[0], a0[1], a0[2], a0[3]);
    attn4_s[c1] = make_float4(a1[0], a1[1], a1[2], a1[3]);
    #pragma unroll
    for (int q = 0; q < 4; ++q) {
        outP[(b * Q_ + q0 + q) * C_ + c0] = a0[q];
        outP[(b * Q_ + q0 + q) * C_ + c1] = a1[q];
    }
    __syncthreads();

    // ---- phase 3: attn_output[q][h] = sum_c attn[q][c]*context[b][c][h]
    const int hg   = t & 31;      // float4 h-chunk: h = hg*4..hg*4+3
    const int crep = t >> 5;      // 16 c-chunks of 64
    float4 acc[4] = {{0,0,0,0},{0,0,0,0},{0,0,0,0},{0,0,0,0}};
    const int cb = crep * 64;
    #pragma unroll 4
    for (int cc = 0; cc < 64; ++cc) {
        const int c = cb + cc;
        const float4 a4 = attn4_s[c];
        const float4 xv = ctx4[(b * C_ + c) * (H_ / 4) + hg];
        acc[0].x += a4.x * xv.x; acc[0].y += a4.x * xv.y; acc[0].z += a4.x * xv.z; acc[0].w += a4.x * xv.w;
        acc[1].x += a4.y * xv.x; acc[1].y += a4.y * xv.y; acc[1].z += a4.y * xv.z; acc[1].w += a4.y * xv.w;
        acc[2].x += a4.z * xv.x; acc[2].y += a4.z * xv.y; acc[2].z += a4.z * xv.z; acc[2].w += a4.z * xv.w;
        acc[3].x += a4.w * xv.x; acc[3].y += a4.w * xv.y; acc[3].z += a4.w * xv.z; acc[3].w += a4.w * xv.w;
    }
    float4* red4 = reinterpret_cast<float4*>(red);
    #pragma unroll
    for (int q = 0; q < 4; ++q)
        red4[(crep * 4 + q) * 32 + hg] = acc[q];
    __syncthreads();
    {
        const int q = t >> 7, h = t & 127;
        float v = 0.f;
        #pragma unroll
        for (int cr = 0; cr < 16; ++cr)
            v += red[(cr * 4 + q) * H_ + h];
        outA[(b * Q_ + q0 + q) * H_ + h] = v;
    }
}

extern "C" void kernel_launch(void* const* d_in, const int* in_sizes, int n_in,
                              void* d_out, int out_size, void* d_ws, size_t ws_size,
                              hipStream_t stream) {
    const float* query   = (const float*)d_in[0];
    const float* context = (const float*)d_in[1];
    const float* Ww      = (const float*)d_in[2];
    const float* bw      = (const float*)d_in[3];
    const float* Ws      = (const float*)d_in[4];
    // d_in[5] (bs) intentionally unused: softmax is shift-invariant and both
    // outputs are post-softmax quantities.

    float* outA = (float*)d_out;                 // attn_output: B*Q*H
    float* outP = outA + B_ * Q_ * H_;           // attn:        B*Q*C

    float* hq = (float*)d_ws;                    // B*Q*H floats (512 KB)
    float* hc = hq + B_ * Q_ * H_;               // B*C*H floats (2 MB)

    hipLaunchKernelGGL(proj_kernel, dim3(640), dim3(128), 0, stream,
                       query, context, Ww, bw, hq, hc);
    hipLaunchKernelGGL(attn_kernel, dim3(256), dim3(512), 0, stream,
                       hq, hc, Ws, context, outA, outP);
}